// Round 7
// baseline (891.587 us; speedup 1.0000x reference)
//
#include <hip/hip_runtime.h>
#include <hip/hip_bf16.h>
#include <math.h>

#define VOCAB 6500
#define EMB   192
#define NH    6
#define NL    6
#define SEQ   512
#define BATCH 32
#define HSZ   32
#define BT    (BATCH*SEQ)   // 16384 tokens

typedef __attribute__((ext_vector_type(8))) short bh8;
typedef __attribute__((ext_vector_type(4))) float f32x4;

#define ATT_SCALE 0.07216878364870323f   // 192^-0.5

static __device__ __forceinline__ short bf16s(float v) {
  __hip_bfloat16 t = __float2bfloat16(v);
  return *reinterpret_cast<short*>(&t);
}

// ---------------------------------------------------------------- embed + PE + LN1(layer0)
__global__ __launch_bounds__(256) void embed_ln(
    const int* __restrict__ idx, const float* __restrict__ tok,
    const float* __restrict__ g, const float* __restrict__ b,
    float* __restrict__ x, __hip_bfloat16* __restrict__ h) {
  const int wid = threadIdx.x >> 6, lane = threadIdx.x & 63;
  const int bt = blockIdx.x * 4 + wid;
  const int t  = bt & (SEQ - 1);
  const int tokid = idx[bt];
  float v[3];
  #pragma unroll
  for (int i = 0; i < 3; ++i) {
    const int e = lane + i * 64;
    const int i2 = e & ~1;
    const float div = expf((float)i2 * (-9.210340371976184f / (float)EMB));
    const float ang = (float)t * div;
    const float pe  = (e & 1) ? cosf(ang) : sinf(ang);
    v[i] = tok[(size_t)tokid * EMB + e] + pe;
  }
  float s = v[0] + v[1] + v[2];
  #pragma unroll
  for (int o = 32; o; o >>= 1) s += __shfl_xor(s, o);
  const float mu = s * (1.0f / (float)EMB);
  float vs = 0.f;
  #pragma unroll
  for (int i = 0; i < 3; ++i) { const float d = v[i] - mu; vs += d * d; }
  #pragma unroll
  for (int o = 32; o; o >>= 1) vs += __shfl_xor(vs, o);
  const float r = rsqrtf(vs * (1.0f / (float)EMB) + 1e-5f);
  float* xr = x + (size_t)bt * EMB;
  __hip_bfloat16* hr = h + (size_t)bt * EMB;
  #pragma unroll
  for (int i = 0; i < 3; ++i) {
    const int e = lane + i * 64;
    xr[e] = v[i];
    hr[e] = __float2bfloat16((v[i] - mu) * r * g[e] + b[e]);
  }
}

// ---------------------------------------------------------------- weight cast+transpose (generic)
__global__ __launch_bounds__(256) void wcast(
    const float* __restrict__ W, __hip_bfloat16* __restrict__ Wt,
    int K, int N, int dstride) {
  __shared__ float t[32][33];
  const float* Ws = W + (size_t)blockIdx.z * K * N;
  __hip_bfloat16* Wd = Wt + (size_t)blockIdx.z * dstride * K;
  const int kt = blockIdx.y * 32, nt = blockIdx.x * 32;
  const int tx = threadIdx.x, ty = threadIdx.y;   // 32 x 8
  for (int i = ty; i < 32; i += 8) {
    const int k = kt + i, n = nt + tx;
    t[i][tx] = (k < K && n < N) ? Ws[(size_t)k * N + n] : 0.f;
  }
  __syncthreads();
  for (int i = ty; i < 32; i += 8) {
    const int n = nt + i, k = kt + tx;
    if (n < N && k < K) Wd[(size_t)n * K + k] = __float2bfloat16(t[tx][i]);
  }
}

// ---------------------------------------------------------------- QKVO cast (4*NL square weights)
__global__ __launch_bounds__(256) void wcast4(
    const float* __restrict__ Wq, const float* __restrict__ Wk,
    const float* __restrict__ Wv, const float* __restrict__ Wo,
    __hip_bfloat16* __restrict__ wqkv, __hip_bfloat16* __restrict__ wot) {
  __shared__ float t[32][33];
  const int z = blockIdx.z, sel = z / NL, layer = z % NL;
  const float* srcs[4] = {Wq, Wk, Wv, Wo};
  const float* Ws = srcs[sel] + (size_t)layer * EMB * EMB;
  __hip_bfloat16* Wd = (sel < 3)
      ? wqkv + ((size_t)layer * 576 + sel * 192) * EMB
      : wot  + (size_t)layer * EMB * EMB;
  const int kt = blockIdx.y * 32, nt = blockIdx.x * 32;
  const int tx = threadIdx.x, ty = threadIdx.y;
  for (int i = ty; i < 32; i += 8)
    t[i][tx] = Ws[(size_t)(kt + i) * EMB + nt + tx];
  __syncthreads();
  for (int i = ty; i < 32; i += 8)
    Wd[(size_t)(nt + i) * EMB + kt + tx] = __float2bfloat16(t[tx][i]);
}

// ---------------------------------------------------------------- big-tile GEMM (BM=128)
// EPI 0: f32 [M,N];  EPI 3: bf16 qkv scatter (q pre-scaled by ATT_SCALE)
template<int EPI, int BN>
__global__ __launch_bounds__(256) void gemm_big(
    const __hip_bfloat16* __restrict__ A, const __hip_bfloat16* __restrict__ Bt,
    void* __restrict__ Cv, int M, int N, int K) {
  constexpr int LDK = 72;
  constexpr int NB = BN / 32;
  constexpr int NC = BN / 16;
  __shared__ short As[128 * LDK];
  __shared__ short Bs[BN * LDK];
  const int tid = threadIdx.x;
  const int wid = tid >> 6, lane = tid & 63;
  const int m0 = blockIdx.y * 128, n0 = blockIdx.x * BN;
  const int srow = tid >> 3, schk = tid & 7;
  const int fr = lane & 15, fg = lane >> 4;

  f32x4 acc[2][NC];
  #pragma unroll
  for (int rt = 0; rt < 2; ++rt)
    #pragma unroll
    for (int ct = 0; ct < NC; ++ct) acc[rt][ct] = (f32x4){0.f, 0.f, 0.f, 0.f};

  for (int k0 = 0; k0 < K; k0 += 64) {
    bh8 av[4], bv[NB];
    #pragma unroll
    for (int p = 0; p < 4; ++p)
      av[p] = *reinterpret_cast<const bh8*>(A + (size_t)(m0 + srow + p * 32) * K + k0 + schk * 8);
    #pragma unroll
    for (int p = 0; p < NB; ++p) {
      const int nr = n0 + srow + p * 32;
      if (nr < N) bv[p] = *reinterpret_cast<const bh8*>(Bt + (size_t)nr * K + k0 + schk * 8);
      else        bv[p] = (bh8){0,0,0,0,0,0,0,0};
    }
    __syncthreads();
    #pragma unroll
    for (int p = 0; p < 4; ++p)
      *reinterpret_cast<bh8*>(As + (srow + p * 32) * LDK + schk * 8) = av[p];
    #pragma unroll
    for (int p = 0; p < NB; ++p)
      *reinterpret_cast<bh8*>(Bs + (srow + p * 32) * LDK + schk * 8) = bv[p];
    __syncthreads();
    #pragma unroll
    for (int s = 0; s < 2; ++s) {
      bh8 af[2];
      #pragma unroll
      for (int rt = 0; rt < 2; ++rt)
        af[rt] = *reinterpret_cast<const bh8*>(As + (wid * 32 + rt * 16 + fr) * LDK + s * 32 + fg * 8);
      #pragma unroll
      for (int ct = 0; ct < NC; ++ct) {
        const bh8 bf_ = *reinterpret_cast<const bh8*>(Bs + (ct * 16 + fr) * LDK + s * 32 + fg * 8);
        #pragma unroll
        for (int rt = 0; rt < 2; ++rt)
          acc[rt][ct] = __builtin_amdgcn_mfma_f32_16x16x32_bf16(af[rt], bf_, acc[rt][ct], 0, 0, 0);
      }
    }
  }

  #pragma unroll
  for (int rt = 0; rt < 2; ++rt)
    #pragma unroll
    for (int ct = 0; ct < NC; ++ct) {
      const int col = n0 + ct * 16 + fr;
      if (col < N) {
        #pragma unroll
        for (int rr = 0; rr < 4; ++rr) {
          const int row = m0 + wid * 32 + rt * 16 + fg * 4 + rr;
          float v = acc[rt][ct][rr];
          if (EPI == 0) {
            ((float*)Cv)[(size_t)row * N + col] = v;
          } else {  // EPI 3: qkv scatter, pre-scale q
            const int part = col / 192, c2 = col - part * 192;
            if (part == 0) v *= ATT_SCALE;
            const int bb = row >> 9, tt = row & (SEQ - 1);
            const int hh = c2 >> 5, dd = c2 & (HSZ - 1);
            ((__hip_bfloat16*)Cv)[(size_t)part * BT * EMB +
                (((size_t)(bb * NH + hh)) * SEQ + tt) * HSZ + dd] = __float2bfloat16(v);
          }
        }
      }
    }
}

// ---------------------------------------------------------------- GEMM+res+LN (final, writes h)
__global__ __launch_bounds__(256) void gemm_resln(
    const __hip_bfloat16* __restrict__ A, const __hip_bfloat16* __restrict__ Bt,
    float* __restrict__ X, __hip_bfloat16* __restrict__ Hout,
    const float* __restrict__ g, const float* __restrict__ b, int K) {
  constexpr int LDK = 72;
  __shared__ short As[64 * LDK];
  __shared__ short Bs[192 * LDK];
  const int tid = threadIdx.x;
  const int wid = tid >> 6, lane = tid & 63;
  const int m0 = blockIdx.x * 64;
  const int srow = tid >> 3, schk = tid & 7;
  const int fr = lane & 15, fg = lane >> 4;

  f32x4 acc[12];
  #pragma unroll
  for (int j = 0; j < 12; ++j) acc[j] = (f32x4){0.f, 0.f, 0.f, 0.f};

  for (int k0 = 0; k0 < K; k0 += 64) {
    bh8 av[2], bv[6];
    #pragma unroll
    for (int p = 0; p < 2; ++p)
      av[p] = *reinterpret_cast<const bh8*>(A + (size_t)(m0 + srow + p * 32) * K + k0 + schk * 8);
    #pragma unroll
    for (int p = 0; p < 6; ++p)
      bv[p] = *reinterpret_cast<const bh8*>(Bt + (size_t)(srow + p * 32) * K + k0 + schk * 8);
    __syncthreads();
    #pragma unroll
    for (int p = 0; p < 2; ++p)
      *reinterpret_cast<bh8*>(As + (srow + p * 32) * LDK + schk * 8) = av[p];
    #pragma unroll
    for (int p = 0; p < 6; ++p)
      *reinterpret_cast<bh8*>(Bs + (srow + p * 32) * LDK + schk * 8) = bv[p];
    __syncthreads();
    #pragma unroll
    for (int s = 0; s < 2; ++s) {
      const bh8 af = *reinterpret_cast<const bh8*>(As + (wid * 16 + fr) * LDK + s * 32 + fg * 8);
      #pragma unroll
      for (int j = 0; j < 12; ++j) {
        const bh8 bf_ = *reinterpret_cast<const bh8*>(Bs + (j * 16 + fr) * LDK + s * 32 + fg * 8);
        acc[j] = __builtin_amdgcn_mfma_f32_16x16x32_bf16(af, bf_, acc[j], 0, 0, 0);
      }
    }
  }

  #pragma unroll
  for (int rr = 0; rr < 4; ++rr) {
    const int row = m0 + wid * 16 + fg * 4 + rr;
    float v[12], sum = 0.f, sq = 0.f;
    #pragma unroll
    for (int j = 0; j < 12; ++j) {
      v[j] = acc[j][rr] + X[(size_t)row * EMB + j * 16 + fr];
      sum += v[j]; sq += v[j] * v[j];
    }
    #pragma unroll
    for (int o = 8; o; o >>= 1) {
      sum += __shfl_xor(sum, o);
      sq  += __shfl_xor(sq,  o);
    }
    const float mu = sum * (1.0f / (float)EMB);
    const float r  = rsqrtf(sq * (1.0f / (float)EMB) - mu * mu + 1e-5f);
    #pragma unroll
    for (int j = 0; j < 12; ++j) {
      const int col = j * 16 + fr;
      X[(size_t)row * EMB + col] = v[j];
      Hout[(size_t)row * EMB + col] = __float2bfloat16((v[j] - mu) * r * g[col] + b[col]);
    }
  }
}

// ---------------------------------------------------------------- fused: res+LN then stream-GEMM
// phase1: X += A@B1t^T (f32 in-place), h = LN(X)*g+b -> LDS
// phase2: stream B2t in 64-col chunks: P2==1: Out2 = gelu(h@B2t^T) bf16 [M,N2]
//                                      P2==2: qkv scatter (q pre-scaled)
template<int P2>
__global__ __launch_bounds__(256) void resln_stream(
    const __hip_bfloat16* __restrict__ A, const __hip_bfloat16* __restrict__ B1t,
    float* __restrict__ X, const float* __restrict__ g, const float* __restrict__ b,
    int K1, const __hip_bfloat16* __restrict__ B2t,
    __hip_bfloat16* __restrict__ Out2, int N2) {
  constexpr int LDK = 72;    // phase-1 k-stride (shorts)
  constexpr int LDH = 200;   // phase-2 row stride (192+8 shorts, 400B = 25x16B)
  __shared__ __align__(16) short lds[64 * LDH * 2];   // 51.2 KB
  short* As  = lds;                 // phase1 [64][72]
  short* Bs  = lds + 64 * LDK;      // phase1 [192][72]
  short* Hs  = lds;                 // phase2 [64][200]
  short* Bs2 = lds + 64 * LDH;      // phase2 [64][200]
  const int tid = threadIdx.x;
  const int wid = tid >> 6, lane = tid & 63;
  const int m0 = blockIdx.x * 64;
  const int srow = tid >> 3, schk = tid & 7;
  const int fr = lane & 15, fg = lane >> 4;

  // ---------------- phase 1
  f32x4 acc[12];
  #pragma unroll
  for (int j = 0; j < 12; ++j) acc[j] = (f32x4){0.f, 0.f, 0.f, 0.f};

  for (int k0 = 0; k0 < K1; k0 += 64) {
    bh8 av[2], bv[6];
    #pragma unroll
    for (int p = 0; p < 2; ++p)
      av[p] = *reinterpret_cast<const bh8*>(A + (size_t)(m0 + srow + p * 32) * K1 + k0 + schk * 8);
    #pragma unroll
    for (int p = 0; p < 6; ++p)
      bv[p] = *reinterpret_cast<const bh8*>(B1t + (size_t)(srow + p * 32) * K1 + k0 + schk * 8);
    __syncthreads();
    #pragma unroll
    for (int p = 0; p < 2; ++p)
      *reinterpret_cast<bh8*>(As + (srow + p * 32) * LDK + schk * 8) = av[p];
    #pragma unroll
    for (int p = 0; p < 6; ++p)
      *reinterpret_cast<bh8*>(Bs + (srow + p * 32) * LDK + schk * 8) = bv[p];
    __syncthreads();
    #pragma unroll
    for (int s = 0; s < 2; ++s) {
      const bh8 af = *reinterpret_cast<const bh8*>(As + (wid * 16 + fr) * LDK + s * 32 + fg * 8);
      #pragma unroll
      for (int j = 0; j < 12; ++j) {
        const bh8 bf_ = *reinterpret_cast<const bh8*>(Bs + (j * 16 + fr) * LDK + s * 32 + fg * 8);
        acc[j] = __builtin_amdgcn_mfma_f32_16x16x32_bf16(af, bf_, acc[j], 0, 0, 0);
      }
    }
  }
  __syncthreads();   // all phase-1 MFMA done before LDS is repurposed

  // residual + LN -> X (global) and Hs (LDS)
  #pragma unroll
  for (int rr = 0; rr < 4; ++rr) {
    const int lrow = wid * 16 + fg * 4 + rr;
    const int row = m0 + lrow;
    float v[12], sum = 0.f, sq = 0.f;
    #pragma unroll
    for (int j = 0; j < 12; ++j) {
      v[j] = acc[j][rr] + X[(size_t)row * EMB + j * 16 + fr];
      sum += v[j]; sq += v[j] * v[j];
    }
    #pragma unroll
    for (int o = 8; o; o >>= 1) {
      sum += __shfl_xor(sum, o);
      sq  += __shfl_xor(sq,  o);
    }
    const float mu = sum * (1.0f / (float)EMB);
    const float r  = rsqrtf(sq * (1.0f / (float)EMB) - mu * mu + 1e-5f);
    #pragma unroll
    for (int j = 0; j < 12; ++j) {
      const int col = j * 16 + fr;
      X[(size_t)row * EMB + col] = v[j];
      Hs[lrow * LDH + col] = bf16s((v[j] - mu) * r * g[col] + b[col]);
    }
  }

  // ---------------- phase 2: stream B2t chunks of 64 cols
  const int nchunk = N2 >> 6;
  const int r2 = tid >> 2, kp = (tid & 3) * 48;  // 4 threads/row, 6x bh8 each
  bh8 bv2[6];
  #pragma unroll
  for (int i = 0; i < 6; ++i)
    bv2[i] = *reinterpret_cast<const bh8*>(B2t + (size_t)r2 * EMB + kp + i * 8);

  for (int c = 0; c < nchunk; ++c) {
    __syncthreads();   // prev chunk consumed (c=0: epilogue disjoint, harmless)
    #pragma unroll
    for (int i = 0; i < 6; ++i)
      *reinterpret_cast<bh8*>(Bs2 + r2 * LDH + kp + i * 8) = bv2[i];
    if (c + 1 < nchunk) {
      #pragma unroll
      for (int i = 0; i < 6; ++i)
        bv2[i] = *reinterpret_cast<const bh8*>(B2t + (size_t)((c + 1) * 64 + r2) * EMB + kp + i * 8);
    }
    __syncthreads();

    f32x4 a2[4];
    #pragma unroll
    for (int ct = 0; ct < 4; ++ct) a2[ct] = (f32x4){0.f, 0.f, 0.f, 0.f};
    #pragma unroll
    for (int s = 0; s < 6; ++s) {
      const bh8 af = *reinterpret_cast<const bh8*>(Hs + (wid * 16 + fr) * LDH + s * 32 + fg * 8);
      #pragma unroll
      for (int ct = 0; ct < 4; ++ct) {
        const bh8 bf_ = *reinterpret_cast<const bh8*>(Bs2 + (ct * 16 + fr) * LDH + s * 32 + fg * 8);
        a2[ct] = __builtin_amdgcn_mfma_f32_16x16x32_bf16(af, bf_, a2[ct], 0, 0, 0);
      }
    }

    #pragma unroll
    for (int ct = 0; ct < 4; ++ct) {
      const int col = c * 64 + ct * 16 + fr;
      #pragma unroll
      for (int rr = 0; rr < 4; ++rr) {
        const int row = m0 + wid * 16 + fg * 4 + rr;
        float v = a2[ct][rr];
        if (P2 == 1) {
          v = 0.5f * v * (1.0f + erff(v * 0.70710678118654752f));
          Out2[(size_t)row * N2 + col] = __float2bfloat16(v);
        } else {  // qkv scatter
          const int part = col / 192, c2 = col - part * 192;
          if (part == 0) v *= ATT_SCALE;
          const int bb = row >> 9, tt = row & (SEQ - 1);
          const int hh = c2 >> 5, dd = c2 & (HSZ - 1);
          Out2[(size_t)part * BT * EMB +
               (((size_t)(bb * NH + hh)) * SEQ + tt) * HSZ + dd] = __float2bfloat16(v);
        }
      }
    }
  }
}

// ---------------------------------------------------------------- flash attention (no-max softmax)
// q pre-scaled by ATT_SCALE at QKV epilogue
__global__ __launch_bounds__(256) void flash_attn(
    const __hip_bfloat16* __restrict__ qh, const __hip_bfloat16* __restrict__ kh,
    const __hip_bfloat16* __restrict__ vh, __hip_bfloat16* __restrict__ att) {
  constexpr int QT = 128, KT = 64, LDP = 72;
  __shared__ __hip_bfloat16 Ks[KT * LDP];
  __shared__ __hip_bfloat16 Vs[HSZ * LDP];
  __shared__ __hip_bfloat16 Ps[4][32 * LDP];
  const int qt = blockIdx.x, h = blockIdx.y, b = blockIdx.z;
  const int tid = threadIdx.x, wid = tid >> 6, lane = tid & 63;
  const int q0 = qt * QT;
  const size_t hb = ((size_t)(b * NH + h)) * SEQ * HSZ;
  const int fr = lane & 15, fg = lane >> 4;

  bh8 aq[2];
  #pragma unroll
  for (int rt = 0; rt < 2; ++rt)
    aq[rt] = *reinterpret_cast<const bh8*>(
        qh + hb + (size_t)(q0 + wid * 32 + rt * 16 + fr) * HSZ + fg * 8);

  f32x4 o[2][2];
  float lp[2][4];
  #pragma unroll
  for (int rt = 0; rt < 2; ++rt) {
    #pragma unroll
    for (int ct = 0; ct < 2; ++ct) o[rt][ct] = (f32x4){0.f, 0.f, 0.f, 0.f};
    #pragma unroll
    for (int rr = 0; rr < 4; ++rr) lp[rt][rr] = 0.f;
  }

  const int nt = 2 * qt + 2;
  const int sr = tid >> 2, d0 = (tid & 3) * 8;
  for (int it = 0; it < nt; ++it) {
    const int s0 = it * KT;
    __syncthreads();
    {
      const bh8 kv8 = *reinterpret_cast<const bh8*>(kh + hb + (size_t)(s0 + sr) * HSZ + d0);
      *reinterpret_cast<bh8*>(&Ks[sr * LDP + d0]) = kv8;
      const bh8 vv8 = *reinterpret_cast<const bh8*>(vh + hb + (size_t)(s0 + sr) * HSZ + d0);
      short tmp[8]; *reinterpret_cast<bh8*>(tmp) = vv8;
      #pragma unroll
      for (int j = 0; j < 8; ++j)
        Vs[(d0 + j) * LDP + sr] = *reinterpret_cast<__hip_bfloat16*>(&tmp[j]);
    }
    __syncthreads();

    // S = Q K^T
    f32x4 sfr[2][4];
    #pragma unroll
    for (int rt = 0; rt < 2; ++rt)
      #pragma unroll
      for (int st = 0; st < 4; ++st) {
        const bh8 bf_ = *reinterpret_cast<const bh8*>(&Ks[(st * 16 + fr) * LDP + fg * 8]);
        sfr[rt][st] = __builtin_amdgcn_mfma_f32_16x16x32_bf16(
            aq[rt], bf_, (f32x4){0.f, 0.f, 0.f, 0.f}, 0, 0, 0);
      }

    // exp (no max subtraction: scores are O(1)); per-thread partial row sums
    __hip_bfloat16* Pw = Ps[wid];
    const bool diag = (s0 + KT - 1 > q0 + wid * 32);
    #pragma unroll
    for (int rt = 0; rt < 2; ++rt) {
      #pragma unroll
      for (int rr = 0; rr < 4; ++rr) {
        float pr[4];
        if (diag) {
          const int qa = q0 + wid * 32 + rt * 16 + fg * 4 + rr;
          #pragma unroll
          for (int st = 0; st < 4; ++st) {
            const int sa = s0 + st * 16 + fr;
            pr[st] = (sa > qa) ? 0.f : __expf(sfr[rt][st][rr]);
          }
        } else {
          #pragma unroll
          for (int st = 0; st < 4; ++st) pr[st] = __expf(sfr[rt][st][rr]);
        }
        lp[rt][rr] += (pr[0] + pr[1]) + (pr[2] + pr[3]);
        #pragma unroll
        for (int st = 0; st < 4; ++st)
          Pw[(rt * 16 + fg * 4 + rr) * LDP + st * 16 + fr] = __float2bfloat16(pr[st]);
      }
    }

    // O += P V
    #pragma unroll
    for (int ks = 0; ks < 2; ++ks) {
      bh8 vb_[2];
      #pragma unroll
      for (int ct = 0; ct < 2; ++ct)
        vb_[ct] = *reinterpret_cast<const bh8*>(&Vs[(ct * 16 + fr) * LDP + ks * 32 + fg * 8]);
      #pragma unroll
      for (int rt = 0; rt < 2; ++rt) {
        const bh8 pa = *reinterpret_cast<const bh8*>(&Pw[(rt * 16 + fr) * LDP + ks * 32 + fg * 8]);
        #pragma unroll
        for (int ct = 0; ct < 2; ++ct)
          o[rt][ct] = __builtin_amdgcn_mfma_f32_16x16x32_bf16(pa, vb_[ct], o[rt][ct], 0, 0, 0);
      }
    }
  }

  // final row-sum reduce + epilogue
  #pragma unroll
  for (int rt = 0; rt < 2; ++rt)
    #pragma unroll
    for (int rr = 0; rr < 4; ++rr) {
      float s = lp[rt][rr];
      #pragma unroll
      for (int off = 8; off; off >>= 1) s += __shfl_xor(s, off);
      const float inv = 1.0f / s;
      const int qa = q0 + wid * 32 + rt * 16 + fg * 4 + rr;
      #pragma unroll
      for (int ct = 0; ct < 2; ++ct) {
        const int d = ct * 16 + fr;
        att[((size_t)(b * SEQ + qa)) * EMB + h * HSZ + d] =
            __float2bfloat16(o[rt][ct][rr] * inv);
      }
    }
}

// ---------------------------------------------------------------- launcher
extern "C" void kernel_launch(void* const* d_in, const int* in_sizes, int n_in,
                              void* d_out, int out_size, void* d_ws, size_t ws_size,
                              hipStream_t stream) {
  const int*   idx   = (const int*)  d_in[0];
  const float* tok   = (const float*)d_in[1];
  const float* Wq    = (const float*)d_in[2];
  const float* Wk    = (const float*)d_in[3];
  const float* Wv    = (const float*)d_in[4];
  const float* Wo    = (const float*)d_in[5];
  const float* W1    = (const float*)d_in[6];
  const float* W2    = (const float*)d_in[7];
  const float* ln1g  = (const float*)d_in[8];
  const float* ln1b  = (const float*)d_in[9];
  const float* ln2g  = (const float*)d_in[10];
  const float* ln2b  = (const float*)d_in[11];
  const float* lnfg  = (const float*)d_in[12];
  const float* lnfb  = (const float*)d_in[13];
  const float* Wlm   = (const float*)d_in[14];
  float* out = (float*)d_out;

  const size_t NTE = (size_t)BT * EMB;
  char* ws = (char*)d_ws;
  float* x   = (float*)ws;                         ws += NTE * 4;
  __hip_bfloat16* qh   = (__hip_bfloat16*)ws;      ws += NTE * 2 * 3;  // q,k,v contiguous
  __hip_bfloat16* h    = (__hip_bfloat16*)ws;      ws += NTE * 2;
  __hip_bfloat16* att  = (__hip_bfloat16*)ws;      ws += NTE * 2;
  __hip_bfloat16* hid  = (__hip_bfloat16*)ws;      ws += NTE * 4 * 2;
  __hip_bfloat16* wqkv = (__hip_bfloat16*)ws;      ws += (size_t)NL * 576 * EMB * 2;
  __hip_bfloat16* wot  = (__hip_bfloat16*)ws;      ws += (size_t)NL * EMB * EMB * 2;
  __hip_bfloat16* w1t  = (__hip_bfloat16*)ws;      ws += (size_t)NL * EMB * EMB * 4 * 2;
  __hip_bfloat16* w2t  = (__hip_bfloat16*)ws;      ws += (size_t)NL * EMB * EMB * 4 * 2;
  __hip_bfloat16* wlt  = (__hip_bfloat16*)ws;

  const dim3 tblk(32, 8);
  wcast4<<<dim3(6, 6, 4 * NL), tblk, 0, stream>>>(Wq, Wk, Wv, Wo, wqkv, wot);
  wcast<<<dim3(24, 6, NL),  tblk, 0, stream>>>(W1,  w1t, EMB, EMB * 4, EMB * 4);
  wcast<<<dim3(6, 24, NL),  tblk, 0, stream>>>(W2,  w2t, EMB * 4, EMB, EMB);
  wcast<<<dim3(204, 6, 1),  tblk, 0, stream>>>(Wlm, wlt, EMB, VOCAB, VOCAB);

  embed_ln<<<BT / 4, 256, 0, stream>>>(idx, tok, ln1g, ln1b, x, h);

  const dim3 gQKV(576 / 64, BT / 128);            // (9,128)
  const dim3 gV  ((VOCAB + 127) / 128, BT / 128); // (51,128)
  const dim3 gA  (SEQ / 128, NH, BATCH);          // (4,6,32)

  gemm_big<3, 64><<<gQKV, 256, 0, stream>>>(h, wqkv, qh, BT, 576, EMB);

  for (int l = 0; l < NL; ++l) {
    const size_t wo = (size_t)l * EMB * EMB;
    const size_t wm = (size_t)l * EMB * EMB * 4;
    flash_attn<<<gA, 256, 0, stream>>>(qh, qh + NTE, qh + 2 * NTE, att);
    // Wo-resLN -> stream W1+gelu
    resln_stream<1><<<BT / 64, 256, 0, stream>>>(
        att, wot + wo, x, ln2g + l * EMB, ln2b + l * EMB, EMB,
        w1t + wm, hid, EMB * 4);
    if (l < NL - 1) {
      // W2-resLN -> stream next-layer QKV
      resln_stream<2><<<BT / 64, 256, 0, stream>>>(
          hid, w2t + wm, x, ln1g + (l + 1) * EMB, ln1b + (l + 1) * EMB, EMB * 4,
          wqkv + (size_t)(l + 1) * 576 * EMB, qh, 576);
    } else {
      gemm_resln<<<BT / 64, 256, 0, stream>>>(hid, w2t + wm, x, h, lnfg, lnfb, EMB * 4);
    }
  }

  gemm_big<0, 128><<<gV, 256, 0, stream>>>(h, wlt, out, BT, VOCAB, EMB);
}

// Round 8
// 706.862 us; speedup vs baseline: 1.2613x; 1.2613x over previous
//
#include <hip/hip_runtime.h>
#include <hip/hip_bf16.h>
#include <math.h>

#define VOCAB 6500
#define EMB   192
#define NH    6
#define NL    6
#define SEQ   512
#define BATCH 32
#define HSZ   32
#define BT    (BATCH*SEQ)   // 16384 tokens

typedef __attribute__((ext_vector_type(8))) short bh8;
typedef __attribute__((ext_vector_type(4))) float f32x4;

#define ATT_SCALE 0.07216878364870323f   // 192^-0.5

// ---------------------------------------------------------------- embed + PE + LN1(layer0)
__global__ __launch_bounds__(256) void embed_ln(
    const int* __restrict__ idx, const float* __restrict__ tok,
    const float* __restrict__ g, const float* __restrict__ b,
    float* __restrict__ x, __hip_bfloat16* __restrict__ h) {
  const int wid = threadIdx.x >> 6, lane = threadIdx.x & 63;
  const int bt = blockIdx.x * 4 + wid;
  const int t  = bt & (SEQ - 1);
  const int tokid = idx[bt];
  float v[3];
  #pragma unroll
  for (int i = 0; i < 3; ++i) {
    const int e = lane + i * 64;
    const int i2 = e & ~1;
    const float div = expf((float)i2 * (-9.210340371976184f / (float)EMB));
    const float ang = (float)t * div;
    const float pe  = (e & 1) ? cosf(ang) : sinf(ang);
    v[i] = tok[(size_t)tokid * EMB + e] + pe;
  }
  float s = v[0] + v[1] + v[2];
  #pragma unroll
  for (int o = 32; o; o >>= 1) s += __shfl_xor(s, o);
  const float mu = s * (1.0f / (float)EMB);
  float vs = 0.f;
  #pragma unroll
  for (int i = 0; i < 3; ++i) { const float d = v[i] - mu; vs += d * d; }
  #pragma unroll
  for (int o = 32; o; o >>= 1) vs += __shfl_xor(vs, o);
  const float r = rsqrtf(vs * (1.0f / (float)EMB) + 1e-5f);
  float* xr = x + (size_t)bt * EMB;
  __hip_bfloat16* hr = h + (size_t)bt * EMB;
  #pragma unroll
  for (int i = 0; i < 3; ++i) {
    const int e = lane + i * 64;
    xr[e] = v[i];
    hr[e] = __float2bfloat16((v[i] - mu) * r * g[e] + b[e]);
  }
}

// ---------------------------------------------------------------- weight cast+transpose (generic)
__global__ __launch_bounds__(256) void wcast(
    const float* __restrict__ W, __hip_bfloat16* __restrict__ Wt,
    int K, int N, int dstride) {
  __shared__ float t[32][33];
  const float* Ws = W + (size_t)blockIdx.z * K * N;
  __hip_bfloat16* Wd = Wt + (size_t)blockIdx.z * dstride * K;
  const int kt = blockIdx.y * 32, nt = blockIdx.x * 32;
  const int tx = threadIdx.x, ty = threadIdx.y;   // 32 x 8
  for (int i = ty; i < 32; i += 8) {
    const int k = kt + i, n = nt + tx;
    t[i][tx] = (k < K && n < N) ? Ws[(size_t)k * N + n] : 0.f;
  }
  __syncthreads();
  for (int i = ty; i < 32; i += 8) {
    const int n = nt + i, k = kt + tx;
    if (n < N && k < K) Wd[(size_t)n * K + k] = __float2bfloat16(t[tx][i]);
  }
}

// ---------------------------------------------------------------- QKVO cast (4*NL square weights)
__global__ __launch_bounds__(256) void wcast4(
    const float* __restrict__ Wq, const float* __restrict__ Wk,
    const float* __restrict__ Wv, const float* __restrict__ Wo,
    __hip_bfloat16* __restrict__ wqkv, __hip_bfloat16* __restrict__ wot) {
  __shared__ float t[32][33];
  const int z = blockIdx.z, sel = z / NL, layer = z % NL;
  const float* srcs[4] = {Wq, Wk, Wv, Wo};
  const float* Ws = srcs[sel] + (size_t)layer * EMB * EMB;
  __hip_bfloat16* Wd = (sel < 3)
      ? wqkv + ((size_t)layer * 576 + sel * 192) * EMB
      : wot  + (size_t)layer * EMB * EMB;
  const int kt = blockIdx.y * 32, nt = blockIdx.x * 32;
  const int tx = threadIdx.x, ty = threadIdx.y;
  for (int i = ty; i < 32; i += 8)
    t[i][tx] = Ws[(size_t)(kt + i) * EMB + nt + tx];
  __syncthreads();
  for (int i = ty; i < 32; i += 8)
    Wd[(size_t)(nt + i) * EMB + kt + tx] = __float2bfloat16(t[tx][i]);
}

// ---------------------------------------------------------------- big-tile GEMM (BM=128), prefetched
// EPI 0: f32 [M,N];  EPI 2: gelu->bf16 [M,N];  EPI 3: bf16 qkv scatter (q pre-scaled)
template<int EPI, int BN>
__global__ __launch_bounds__(256) void gemm_big(
    const __hip_bfloat16* __restrict__ A, const __hip_bfloat16* __restrict__ Bt,
    void* __restrict__ Cv, int M, int N, int K) {
  constexpr int LDK = 72;
  constexpr int NB = BN / 32;
  constexpr int NC = BN / 16;
  __shared__ short As[128 * LDK];
  __shared__ short Bs[BN * LDK];
  const int tid = threadIdx.x;
  const int wid = tid >> 6, lane = tid & 63;
  const int m0 = blockIdx.y * 128, n0 = blockIdx.x * BN;
  const int srow = tid >> 3, schk = tid & 7;
  const int fr = lane & 15, fg = lane >> 4;

  f32x4 acc[2][NC];
  #pragma unroll
  for (int rt = 0; rt < 2; ++rt)
    #pragma unroll
    for (int ct = 0; ct < NC; ++ct) acc[rt][ct] = (f32x4){0.f, 0.f, 0.f, 0.f};

  bh8 av[4], bv[NB];
  #pragma unroll
  for (int p = 0; p < 4; ++p)
    av[p] = *reinterpret_cast<const bh8*>(A + (size_t)(m0 + srow + p * 32) * K + schk * 8);
  #pragma unroll
  for (int p = 0; p < NB; ++p) {
    const int nr = n0 + srow + p * 32;
    if (nr < N) bv[p] = *reinterpret_cast<const bh8*>(Bt + (size_t)nr * K + schk * 8);
    else        bv[p] = (bh8){0,0,0,0,0,0,0,0};
  }

  for (int k0 = 0; k0 < K; k0 += 64) {
    __syncthreads();
    #pragma unroll
    for (int p = 0; p < 4; ++p)
      *reinterpret_cast<bh8*>(As + (srow + p * 32) * LDK + schk * 8) = av[p];
    #pragma unroll
    for (int p = 0; p < NB; ++p)
      *reinterpret_cast<bh8*>(Bs + (srow + p * 32) * LDK + schk * 8) = bv[p];
    __syncthreads();
    // prefetch next tile (issued before MFMA; latency hides under compute)
    if (k0 + 64 < K) {
      const int kn = k0 + 64 + schk * 8;
      #pragma unroll
      for (int p = 0; p < 4; ++p)
        av[p] = *reinterpret_cast<const bh8*>(A + (size_t)(m0 + srow + p * 32) * K + kn);
      #pragma unroll
      for (int p = 0; p < NB; ++p) {
        const int nr = n0 + srow + p * 32;
        if (nr < N) bv[p] = *reinterpret_cast<const bh8*>(Bt + (size_t)nr * K + kn);
      }
    }
    #pragma unroll
    for (int s = 0; s < 2; ++s) {
      bh8 af[2];
      #pragma unroll
      for (int rt = 0; rt < 2; ++rt)
        af[rt] = *reinterpret_cast<const bh8*>(As + (wid * 32 + rt * 16 + fr) * LDK + s * 32 + fg * 8);
      #pragma unroll
      for (int ct = 0; ct < NC; ++ct) {
        const bh8 bf_ = *reinterpret_cast<const bh8*>(Bs + (ct * 16 + fr) * LDK + s * 32 + fg * 8);
        #pragma unroll
        for (int rt = 0; rt < 2; ++rt)
          acc[rt][ct] = __builtin_amdgcn_mfma_f32_16x16x32_bf16(af[rt], bf_, acc[rt][ct], 0, 0, 0);
      }
    }
  }

  #pragma unroll
  for (int rt = 0; rt < 2; ++rt)
    #pragma unroll
    for (int ct = 0; ct < NC; ++ct) {
      const int col = n0 + ct * 16 + fr;
      if (col < N) {
        #pragma unroll
        for (int rr = 0; rr < 4; ++rr) {
          const int row = m0 + wid * 32 + rt * 16 + fg * 4 + rr;
          float v = acc[rt][ct][rr];
          if (EPI == 0) {
            ((float*)Cv)[(size_t)row * N + col] = v;
          } else if (EPI == 2) {
            v = 0.5f * v * (1.0f + erff(v * 0.70710678118654752f));
            ((__hip_bfloat16*)Cv)[(size_t)row * N + col] = __float2bfloat16(v);
          } else {  // EPI 3: qkv scatter, pre-scale q
            const int part = col / 192, c2 = col - part * 192;
            if (part == 0) v *= ATT_SCALE;
            const int bb = row >> 9, tt = row & (SEQ - 1);
            const int hh = c2 >> 5, dd = c2 & (HSZ - 1);
            ((__hip_bfloat16*)Cv)[(size_t)part * BT * EMB +
                (((size_t)(bb * NH + hh)) * SEQ + tt) * HSZ + dd] = __float2bfloat16(v);
          }
        }
      }
    }
}

// ---------------------------------------------------------------- GEMM+res+LN, BM=32, 2 waves, prefetched
// X += A@Bt^T (f32 in-place); Hout = LN(X)*g+b (bf16)
__global__ __launch_bounds__(128) void gemm_resln(
    const __hip_bfloat16* __restrict__ A, const __hip_bfloat16* __restrict__ Bt,
    float* __restrict__ X, __hip_bfloat16* __restrict__ Hout,
    const float* __restrict__ g, const float* __restrict__ b, int K) {
  constexpr int LDK = 72;
  __shared__ short As[32 * LDK];
  __shared__ short Bs[192 * LDK];
  const int tid = threadIdx.x;            // 0..127, 2 waves
  const int wid = tid >> 6, lane = tid & 63;
  const int m0 = blockIdx.x * 32;
  const int srow = tid >> 3, schk = tid & 7;   // srow 0..15
  const int fr = lane & 15, fg = lane >> 4;

  f32x4 acc[12];
  #pragma unroll
  for (int j = 0; j < 12; ++j) acc[j] = (f32x4){0.f, 0.f, 0.f, 0.f};

  bh8 av[2], bv[12];
  #pragma unroll
  for (int p = 0; p < 2; ++p)
    av[p] = *reinterpret_cast<const bh8*>(A + (size_t)(m0 + srow + p * 16) * K + schk * 8);
  #pragma unroll
  for (int p = 0; p < 12; ++p)
    bv[p] = *reinterpret_cast<const bh8*>(Bt + (size_t)(srow + p * 16) * K + schk * 8);

  for (int k0 = 0; k0 < K; k0 += 64) {
    __syncthreads();
    #pragma unroll
    for (int p = 0; p < 2; ++p)
      *reinterpret_cast<bh8*>(As + (srow + p * 16) * LDK + schk * 8) = av[p];
    #pragma unroll
    for (int p = 0; p < 12; ++p)
      *reinterpret_cast<bh8*>(Bs + (srow + p * 16) * LDK + schk * 8) = bv[p];
    __syncthreads();
    if (k0 + 64 < K) {
      const int kn = k0 + 64 + schk * 8;
      #pragma unroll
      for (int p = 0; p < 2; ++p)
        av[p] = *reinterpret_cast<const bh8*>(A + (size_t)(m0 + srow + p * 16) * K + kn);
      #pragma unroll
      for (int p = 0; p < 12; ++p)
        bv[p] = *reinterpret_cast<const bh8*>(Bt + (size_t)(srow + p * 16) * K + kn);
    }
    #pragma unroll
    for (int s = 0; s < 2; ++s) {
      const bh8 af = *reinterpret_cast<const bh8*>(As + (wid * 16 + fr) * LDK + s * 32 + fg * 8);
      #pragma unroll
      for (int j = 0; j < 12; ++j) {
        const bh8 bf_ = *reinterpret_cast<const bh8*>(Bs + (j * 16 + fr) * LDK + s * 32 + fg * 8);
        acc[j] = __builtin_amdgcn_mfma_f32_16x16x32_bf16(af, bf_, acc[j], 0, 0, 0);
      }
    }
  }

  #pragma unroll
  for (int rr = 0; rr < 4; ++rr) {
    const int row = m0 + wid * 16 + fg * 4 + rr;
    float v[12], sum = 0.f, sq = 0.f;
    #pragma unroll
    for (int j = 0; j < 12; ++j) {
      v[j] = acc[j][rr] + X[(size_t)row * EMB + j * 16 + fr];
      sum += v[j]; sq += v[j] * v[j];
    }
    #pragma unroll
    for (int o = 8; o; o >>= 1) {
      sum += __shfl_xor(sum, o);
      sq  += __shfl_xor(sq,  o);
    }
    const float mu = sum * (1.0f / (float)EMB);
    const float r  = rsqrtf(sq * (1.0f / (float)EMB) - mu * mu + 1e-5f);
    #pragma unroll
    for (int j = 0; j < 12; ++j) {
      const int col = j * 16 + fr;
      X[(size_t)row * EMB + col] = v[j];
      Hout[(size_t)row * EMB + col] = __float2bfloat16((v[j] - mu) * r * g[col] + b[col]);
    }
  }
}

// ---------------------------------------------------------------- flash attention (no-max softmax), prefetched
// q pre-scaled by ATT_SCALE at QKV epilogue
__global__ __launch_bounds__(256) void flash_attn(
    const __hip_bfloat16* __restrict__ qh, const __hip_bfloat16* __restrict__ kh,
    const __hip_bfloat16* __restrict__ vh, __hip_bfloat16* __restrict__ att) {
  constexpr int QT = 128, KT = 64, LDP = 72;
  __shared__ __hip_bfloat16 Ks[KT * LDP];
  __shared__ __hip_bfloat16 Vs[HSZ * LDP];
  __shared__ __hip_bfloat16 Ps[4][32 * LDP];
  const int qt = blockIdx.x, h = blockIdx.y, b = blockIdx.z;
  const int tid = threadIdx.x, wid = tid >> 6, lane = tid & 63;
  const int q0 = qt * QT;
  const size_t hb = ((size_t)(b * NH + h)) * SEQ * HSZ;
  const int fr = lane & 15, fg = lane >> 4;

  bh8 aq[2];
  #pragma unroll
  for (int rt = 0; rt < 2; ++rt)
    aq[rt] = *reinterpret_cast<const bh8*>(
        qh + hb + (size_t)(q0 + wid * 32 + rt * 16 + fr) * HSZ + fg * 8);

  f32x4 o[2][2];
  float lp[2][4];
  #pragma unroll
  for (int rt = 0; rt < 2; ++rt) {
    #pragma unroll
    for (int ct = 0; ct < 2; ++ct) o[rt][ct] = (f32x4){0.f, 0.f, 0.f, 0.f};
    #pragma unroll
    for (int rr = 0; rr < 4; ++rr) lp[rt][rr] = 0.f;
  }

  const int nt = 2 * qt + 2;
  const int sr = tid >> 2, d0 = (tid & 3) * 8;
  bh8 kv8 = *reinterpret_cast<const bh8*>(kh + hb + (size_t)sr * HSZ + d0);
  bh8 vv8 = *reinterpret_cast<const bh8*>(vh + hb + (size_t)sr * HSZ + d0);

  for (int it = 0; it < nt; ++it) {
    const int s0 = it * KT;
    __syncthreads();
    {
      *reinterpret_cast<bh8*>(&Ks[sr * LDP + d0]) = kv8;
      short tmp[8]; *reinterpret_cast<bh8*>(tmp) = vv8;
      #pragma unroll
      for (int j = 0; j < 8; ++j)
        Vs[(d0 + j) * LDP + sr] = *reinterpret_cast<__hip_bfloat16*>(&tmp[j]);
    }
    __syncthreads();
    if (it + 1 < nt) {
      const size_t nb_ = hb + (size_t)(s0 + KT + sr) * HSZ + d0;
      kv8 = *reinterpret_cast<const bh8*>(kh + nb_);
      vv8 = *reinterpret_cast<const bh8*>(vh + nb_);
    }

    // S = Q K^T
    f32x4 sfr[2][4];
    #pragma unroll
    for (int rt = 0; rt < 2; ++rt)
      #pragma unroll
      for (int st = 0; st < 4; ++st) {
        const bh8 bf_ = *reinterpret_cast<const bh8*>(&Ks[(st * 16 + fr) * LDP + fg * 8]);
        sfr[rt][st] = __builtin_amdgcn_mfma_f32_16x16x32_bf16(
            aq[rt], bf_, (f32x4){0.f, 0.f, 0.f, 0.f}, 0, 0, 0);
      }

    // exp (no max subtraction: scores are O(1)); per-thread partial row sums
    __hip_bfloat16* Pw = Ps[wid];
    const bool diag = (s0 + KT - 1 > q0 + wid * 32);
    #pragma unroll
    for (int rt = 0; rt < 2; ++rt) {
      #pragma unroll
      for (int rr = 0; rr < 4; ++rr) {
        float pr[4];
        if (diag) {
          const int qa = q0 + wid * 32 + rt * 16 + fg * 4 + rr;
          #pragma unroll
          for (int st = 0; st < 4; ++st) {
            const int sa = s0 + st * 16 + fr;
            pr[st] = (sa > qa) ? 0.f : __expf(sfr[rt][st][rr]);
          }
        } else {
          #pragma unroll
          for (int st = 0; st < 4; ++st) pr[st] = __expf(sfr[rt][st][rr]);
        }
        lp[rt][rr] += (pr[0] + pr[1]) + (pr[2] + pr[3]);
        #pragma unroll
        for (int st = 0; st < 4; ++st)
          Pw[(rt * 16 + fg * 4 + rr) * LDP + st * 16 + fr] = __float2bfloat16(pr[st]);
      }
    }

    // O += P V
    #pragma unroll
    for (int ks = 0; ks < 2; ++ks) {
      bh8 vb_[2];
      #pragma unroll
      for (int ct = 0; ct < 2; ++ct)
        vb_[ct] = *reinterpret_cast<const bh8*>(&Vs[(ct * 16 + fr) * LDP + ks * 32 + fg * 8]);
      #pragma unroll
      for (int rt = 0; rt < 2; ++rt) {
        const bh8 pa = *reinterpret_cast<const bh8*>(&Pw[(rt * 16 + fr) * LDP + ks * 32 + fg * 8]);
        #pragma unroll
        for (int ct = 0; ct < 2; ++ct)
          o[rt][ct] = __builtin_amdgcn_mfma_f32_16x16x32_bf16(pa, vb_[ct], o[rt][ct], 0, 0, 0);
      }
    }
  }

  // final row-sum reduce + epilogue
  #pragma unroll
  for (int rt = 0; rt < 2; ++rt)
    #pragma unroll
    for (int rr = 0; rr < 4; ++rr) {
      float s = lp[rt][rr];
      #pragma unroll
      for (int off = 8; off; off >>= 1) s += __shfl_xor(s, off);
      const float inv = 1.0f / s;
      const int qa = q0 + wid * 32 + rt * 16 + fg * 4 + rr;
      #pragma unroll
      for (int ct = 0; ct < 2; ++ct) {
        const int d = ct * 16 + fr;
        att[((size_t)(b * SEQ + qa)) * EMB + h * HSZ + d] =
            __float2bfloat16(o[rt][ct][rr] * inv);
      }
    }
}

// ---------------------------------------------------------------- launcher
extern "C" void kernel_launch(void* const* d_in, const int* in_sizes, int n_in,
                              void* d_out, int out_size, void* d_ws, size_t ws_size,
                              hipStream_t stream) {
  const int*   idx   = (const int*)  d_in[0];
  const float* tok   = (const float*)d_in[1];
  const float* Wq    = (const float*)d_in[2];
  const float* Wk    = (const float*)d_in[3];
  const float* Wv    = (const float*)d_in[4];
  const float* Wo    = (const float*)d_in[5];
  const float* W1    = (const float*)d_in[6];
  const float* W2    = (const float*)d_in[7];
  const float* ln1g  = (const float*)d_in[8];
  const float* ln1b  = (const float*)d_in[9];
  const float* ln2g  = (const float*)d_in[10];
  const float* ln2b  = (const float*)d_in[11];
  const float* lnfg  = (const float*)d_in[12];
  const float* lnfb  = (const float*)d_in[13];
  const float* Wlm   = (const float*)d_in[14];
  float* out = (float*)d_out;

  const size_t NTE = (size_t)BT * EMB;
  char* ws = (char*)d_ws;
  float* x   = (float*)ws;                         ws += NTE * 4;
  __hip_bfloat16* qh   = (__hip_bfloat16*)ws;      ws += NTE * 2 * 3;  // q,k,v contiguous
  __hip_bfloat16* h    = (__hip_bfloat16*)ws;      ws += NTE * 2;
  __hip_bfloat16* att  = (__hip_bfloat16*)ws;      ws += NTE * 2;
  __hip_bfloat16* hid  = (__hip_bfloat16*)ws;      ws += NTE * 4 * 2;
  __hip_bfloat16* wqkv = (__hip_bfloat16*)ws;      ws += (size_t)NL * 576 * EMB * 2;
  __hip_bfloat16* wot  = (__hip_bfloat16*)ws;      ws += (size_t)NL * EMB * EMB * 2;
  __hip_bfloat16* w1t  = (__hip_bfloat16*)ws;      ws += (size_t)NL * EMB * EMB * 4 * 2;
  __hip_bfloat16* w2t  = (__hip_bfloat16*)ws;      ws += (size_t)NL * EMB * EMB * 4 * 2;
  __hip_bfloat16* wlt  = (__hip_bfloat16*)ws;

  const dim3 tblk(32, 8);
  wcast4<<<dim3(6, 6, 4 * NL), tblk, 0, stream>>>(Wq, Wk, Wv, Wo, wqkv, wot);
  wcast<<<dim3(24, 6, NL),  tblk, 0, stream>>>(W1,  w1t, EMB, EMB * 4, EMB * 4);
  wcast<<<dim3(6, 24, NL),  tblk, 0, stream>>>(W2,  w2t, EMB * 4, EMB, EMB);
  wcast<<<dim3(204, 6, 1),  tblk, 0, stream>>>(Wlm, wlt, EMB, VOCAB, VOCAB);

  embed_ln<<<BT / 4, 256, 0, stream>>>(idx, tok, ln1g, ln1b, x, h);

  const dim3 gQKV(576 / 64, BT / 128);            // (9,128)
  const dim3 gM  (EMB * 4 / 64, BT / 128);        // (12,128)
  const dim3 gV  ((VOCAB + 127) / 128, BT / 128); // (51,128)
  const dim3 gA  (SEQ / 128, NH, BATCH);          // (4,6,32)

  for (int l = 0; l < NL; ++l) {
    const size_t wo = (size_t)l * EMB * EMB;
    const size_t wm = (size_t)l * EMB * EMB * 4;
    gemm_big<3, 64><<<gQKV, 256, 0, stream>>>(h, wqkv + (size_t)l * 576 * EMB, qh, BT, 576, EMB);
    flash_attn<<<gA, 256, 0, stream>>>(qh, qh + NTE, qh + 2 * NTE, att);
    gemm_resln<<<BT / 32, 128, 0, stream>>>(att, wot + wo, x, h,
                                            ln2g + l * EMB, ln2b + l * EMB, EMB);
    gemm_big<2, 64><<<gM, 256, 0, stream>>>(h, w1t + wm, hid, BT, EMB * 4, EMB);
    const float* ng = (l == NL - 1) ? lnfg : ln1g + (l + 1) * EMB;
    const float* nb = (l == NL - 1) ? lnfb : ln1b + (l + 1) * EMB;
    gemm_resln<<<BT / 32, 128, 0, stream>>>(hid, w2t + wm, x, h, ng, nb, EMB * 4);
  }

  gemm_big<0, 128><<<gV, 256, 0, stream>>>(h, wlt, out, BT, VOCAB, EMB);
}

// Round 9
// 704.763 us; speedup vs baseline: 1.2651x; 1.0030x over previous
//
#include <hip/hip_runtime.h>
#include <hip/hip_bf16.h>
#include <math.h>

#define VOCAB 6500
#define EMB   192
#define NH    6
#define NL    6
#define SEQ   512
#define BATCH 32
#define HSZ   32
#define BT    (BATCH*SEQ)   // 16384 tokens

typedef __attribute__((ext_vector_type(8))) short bh8;
typedef __attribute__((ext_vector_type(4))) float f32x4;

#define ATT_SCALE 0.07216878364870323f   // 192^-0.5

// ---------------------------------------------------------------- embed + PE + LN1(layer0)
__global__ __launch_bounds__(256) void embed_ln(
    const int* __restrict__ idx, const float* __restrict__ tok,
    const float* __restrict__ g, const float* __restrict__ b,
    float* __restrict__ x, __hip_bfloat16* __restrict__ h) {
  const int wid = threadIdx.x >> 6, lane = threadIdx.x & 63;
  const int bt = blockIdx.x * 4 + wid;
  const int t  = bt & (SEQ - 1);
  const int tokid = idx[bt];
  float v[3];
  #pragma unroll
  for (int i = 0; i < 3; ++i) {
    const int e = lane + i * 64;
    const int i2 = e & ~1;
    const float div = expf((float)i2 * (-9.210340371976184f / (float)EMB));
    const float ang = (float)t * div;
    const float pe  = (e & 1) ? cosf(ang) : sinf(ang);
    v[i] = tok[(size_t)tokid * EMB + e] + pe;
  }
  float s = v[0] + v[1] + v[2];
  #pragma unroll
  for (int o = 32; o; o >>= 1) s += __shfl_xor(s, o);
  const float mu = s * (1.0f / (float)EMB);
  float vs = 0.f;
  #pragma unroll
  for (int i = 0; i < 3; ++i) { const float d = v[i] - mu; vs += d * d; }
  #pragma unroll
  for (int o = 32; o; o >>= 1) vs += __shfl_xor(vs, o);
  const float r = rsqrtf(vs * (1.0f / (float)EMB) + 1e-5f);
  float* xr = x + (size_t)bt * EMB;
  __hip_bfloat16* hr = h + (size_t)bt * EMB;
  #pragma unroll
  for (int i = 0; i < 3; ++i) {
    const int e = lane + i * 64;
    xr[e] = v[i];
    hr[e] = __float2bfloat16((v[i] - mu) * r * g[e] + b[e]);
  }
}

// ---------------------------------------------------------------- unified weight prep (all casts, one dispatch)
// flat job table: [0,864) qkv/o; [864,1728) W1; [1728,2592) W2; [2592,3816) Wlm
__global__ __launch_bounds__(256) void wprep(
    const float* __restrict__ Wq, const float* __restrict__ Wk,
    const float* __restrict__ Wv, const float* __restrict__ Wo,
    const float* __restrict__ W1, const float* __restrict__ W2,
    const float* __restrict__ Wlm,
    __hip_bfloat16* __restrict__ wqkv, __hip_bfloat16* __restrict__ wot,
    __hip_bfloat16* __restrict__ w1t,  __hip_bfloat16* __restrict__ w2t,
    __hip_bfloat16* __restrict__ wlt) {
  __shared__ float t[32][33];
  const int id = blockIdx.x;
  const float* Ws; __hip_bfloat16* Wd; int K, N, bx, by;
  if (id < 864) {                      // Wq/Wk/Wv/Wo: 24 mats x 36 tiles
    const int z = id / 36, rem = id % 36;
    const int sel = z / NL, layer = z % NL;
    by = rem / 6; bx = rem % 6; K = 192; N = 192;
    const float* s4[4] = {Wq, Wk, Wv, Wo};
    Ws = s4[sel] + (size_t)layer * 192 * 192;
    Wd = (sel < 3) ? wqkv + ((size_t)layer * 576 + sel * 192) * 192
                   : wot  + (size_t)layer * 192 * 192;
  } else if (id < 1728) {              // W1: [192][768] -> [768][192]
    const int j = id - 864, layer = j / 144, rem = j % 144;
    bx = rem % 24; by = rem / 24; K = 192; N = 768;
    Ws = W1 + (size_t)layer * 192 * 768;
    Wd = w1t + (size_t)layer * 768 * 192;
  } else if (id < 2592) {              // W2: [768][192] -> [192][768]
    const int j = id - 1728, layer = j / 144, rem = j % 144;
    bx = rem % 6; by = rem / 6; K = 768; N = 192;
    Ws = W2 + (size_t)layer * 768 * 192;
    Wd = w2t + (size_t)layer * 192 * 768;
  } else {                             // Wlm: [192][6500] -> [6500][192]
    const int j = id - 2592;
    bx = j % 204; by = j / 204; K = 192; N = VOCAB;
    Ws = Wlm; Wd = wlt;
  }
  const int kt = by * 32, nt = bx * 32;
  const int tx = threadIdx.x & 31, ty = threadIdx.x >> 5;
  for (int i = ty; i < 32; i += 8) {
    const int k = kt + i, n = nt + tx;
    t[i][tx] = (k < K && n < N) ? Ws[(size_t)k * N + n] : 0.f;
  }
  __syncthreads();
  for (int i = ty; i < 32; i += 8) {
    const int n = nt + i, k = kt + tx;
    if (n < N && k < K) Wd[(size_t)n * K + k] = __float2bfloat16(t[tx][i]);
  }
}

// ---------------------------------------------------------------- big-tile GEMM (BM=128), prefetched
// EPI 0: f32 [M,N];  EPI 2: gelu->bf16 [M,N];  EPI 3: bf16 qkv scatter (q pre-scaled)
template<int EPI, int BN>
__global__ __launch_bounds__(256) void gemm_big(
    const __hip_bfloat16* __restrict__ A, const __hip_bfloat16* __restrict__ Bt,
    void* __restrict__ Cv, int M, int N, int K) {
  constexpr int LDK = 72;
  constexpr int NB = BN / 32;
  constexpr int NC = BN / 16;
  __shared__ short As[128 * LDK];
  __shared__ short Bs[BN * LDK];
  const int tid = threadIdx.x;
  const int wid = tid >> 6, lane = tid & 63;
  const int m0 = blockIdx.y * 128, n0 = blockIdx.x * BN;
  const int srow = tid >> 3, schk = tid & 7;
  const int fr = lane & 15, fg = lane >> 4;

  f32x4 acc[2][NC];
  #pragma unroll
  for (int rt = 0; rt < 2; ++rt)
    #pragma unroll
    for (int ct = 0; ct < NC; ++ct) acc[rt][ct] = (f32x4){0.f, 0.f, 0.f, 0.f};

  bh8 av[4], bv[NB];
  #pragma unroll
  for (int p = 0; p < 4; ++p)
    av[p] = *reinterpret_cast<const bh8*>(A + (size_t)(m0 + srow + p * 32) * K + schk * 8);
  #pragma unroll
  for (int p = 0; p < NB; ++p) {
    const int nr = n0 + srow + p * 32;
    if (nr < N) bv[p] = *reinterpret_cast<const bh8*>(Bt + (size_t)nr * K + schk * 8);
    else        bv[p] = (bh8){0,0,0,0,0,0,0,0};
  }

  for (int k0 = 0; k0 < K; k0 += 64) {
    __syncthreads();
    #pragma unroll
    for (int p = 0; p < 4; ++p)
      *reinterpret_cast<bh8*>(As + (srow + p * 32) * LDK + schk * 8) = av[p];
    #pragma unroll
    for (int p = 0; p < NB; ++p)
      *reinterpret_cast<bh8*>(Bs + (srow + p * 32) * LDK + schk * 8) = bv[p];
    __syncthreads();
    // prefetch next tile (issued before MFMA; latency hides under compute)
    if (k0 + 64 < K) {
      const int kn = k0 + 64 + schk * 8;
      #pragma unroll
      for (int p = 0; p < 4; ++p)
        av[p] = *reinterpret_cast<const bh8*>(A + (size_t)(m0 + srow + p * 32) * K + kn);
      #pragma unroll
      for (int p = 0; p < NB; ++p) {
        const int nr = n0 + srow + p * 32;
        if (nr < N) bv[p] = *reinterpret_cast<const bh8*>(Bt + (size_t)nr * K + kn);
      }
    }
    #pragma unroll
    for (int s = 0; s < 2; ++s) {
      bh8 af[2];
      #pragma unroll
      for (int rt = 0; rt < 2; ++rt)
        af[rt] = *reinterpret_cast<const bh8*>(As + (wid * 32 + rt * 16 + fr) * LDK + s * 32 + fg * 8);
      #pragma unroll
      for (int ct = 0; ct < NC; ++ct) {
        const bh8 bf_ = *reinterpret_cast<const bh8*>(Bs + (ct * 16 + fr) * LDK + s * 32 + fg * 8);
        #pragma unroll
        for (int rt = 0; rt < 2; ++rt)
          acc[rt][ct] = __builtin_amdgcn_mfma_f32_16x16x32_bf16(af[rt], bf_, acc[rt][ct], 0, 0, 0);
      }
    }
  }

  #pragma unroll
  for (int rt = 0; rt < 2; ++rt)
    #pragma unroll
    for (int ct = 0; ct < NC; ++ct) {
      const int col = n0 + ct * 16 + fr;
      if (col < N) {
        #pragma unroll
        for (int rr = 0; rr < 4; ++rr) {
          const int row = m0 + wid * 32 + rt * 16 + fg * 4 + rr;
          float v = acc[rt][ct][rr];
          if (EPI == 0) {
            ((float*)Cv)[(size_t)row * N + col] = v;
          } else if (EPI == 2) {
            v = 0.5f * v * (1.0f + erff(v * 0.70710678118654752f));
            ((__hip_bfloat16*)Cv)[(size_t)row * N + col] = __float2bfloat16(v);
          } else {  // EPI 3: qkv scatter, pre-scale q
            const int part = col / 192, c2 = col - part * 192;
            if (part == 0) v *= ATT_SCALE;
            const int bb = row >> 9, tt = row & (SEQ - 1);
            const int hh = c2 >> 5, dd = c2 & (HSZ - 1);
            ((__hip_bfloat16*)Cv)[(size_t)part * BT * EMB +
                (((size_t)(bb * NH + hh)) * SEQ + tt) * HSZ + dd] = __float2bfloat16(v);
          }
        }
      }
    }
}

// ---------------------------------------------------------------- GEMM+res+LN, BM=32, 2 waves, prefetched
// X += A@Bt^T (f32 in-place); Hout = LN(X)*g+b (bf16)
__global__ __launch_bounds__(128) void gemm_resln(
    const __hip_bfloat16* __restrict__ A, const __hip_bfloat16* __restrict__ Bt,
    float* __restrict__ X, __hip_bfloat16* __restrict__ Hout,
    const float* __restrict__ g, const float* __restrict__ b, int K) {
  constexpr int LDK = 72;
  __shared__ short As[32 * LDK];
  __shared__ short Bs[192 * LDK];
  const int tid = threadIdx.x;            // 0..127, 2 waves
  const int wid = tid >> 6, lane = tid & 63;
  const int m0 = blockIdx.x * 32;
  const int srow = tid >> 3, schk = tid & 7;   // srow 0..15
  const int fr = lane & 15, fg = lane >> 4;

  f32x4 acc[12];
  #pragma unroll
  for (int j = 0; j < 12; ++j) acc[j] = (f32x4){0.f, 0.f, 0.f, 0.f};

  bh8 av[2], bv[12];
  #pragma unroll
  for (int p = 0; p < 2; ++p)
    av[p] = *reinterpret_cast<const bh8*>(A + (size_t)(m0 + srow + p * 16) * K + schk * 8);
  #pragma unroll
  for (int p = 0; p < 12; ++p)
    bv[p] = *reinterpret_cast<const bh8*>(Bt + (size_t)(srow + p * 16) * K + schk * 8);

  for (int k0 = 0; k0 < K; k0 += 64) {
    __syncthreads();
    #pragma unroll
    for (int p = 0; p < 2; ++p)
      *reinterpret_cast<bh8*>(As + (srow + p * 16) * LDK + schk * 8) = av[p];
    #pragma unroll
    for (int p = 0; p < 12; ++p)
      *reinterpret_cast<bh8*>(Bs + (srow + p * 16) * LDK + schk * 8) = bv[p];
    __syncthreads();
    if (k0 + 64 < K) {
      const int kn = k0 + 64 + schk * 8;
      #pragma unroll
      for (int p = 0; p < 2; ++p)
        av[p] = *reinterpret_cast<const bh8*>(A + (size_t)(m0 + srow + p * 16) * K + kn);
      #pragma unroll
      for (int p = 0; p < 12; ++p)
        bv[p] = *reinterpret_cast<const bh8*>(Bt + (size_t)(srow + p * 16) * K + kn);
    }
    #pragma unroll
    for (int s = 0; s < 2; ++s) {
      const bh8 af = *reinterpret_cast<const bh8*>(As + (wid * 16 + fr) * LDK + s * 32 + fg * 8);
      #pragma unroll
      for (int j = 0; j < 12; ++j) {
        const bh8 bf_ = *reinterpret_cast<const bh8*>(Bs + (j * 16 + fr) * LDK + s * 32 + fg * 8);
        acc[j] = __builtin_amdgcn_mfma_f32_16x16x32_bf16(af, bf_, acc[j], 0, 0, 0);
      }
    }
  }

  #pragma unroll
  for (int rr = 0; rr < 4; ++rr) {
    const int row = m0 + wid * 16 + fg * 4 + rr;
    float v[12], sum = 0.f, sq = 0.f;
    #pragma unroll
    for (int j = 0; j < 12; ++j) {
      v[j] = acc[j][rr] + X[(size_t)row * EMB + j * 16 + fr];
      sum += v[j]; sq += v[j] * v[j];
    }
    #pragma unroll
    for (int o = 8; o; o >>= 1) {
      sum += __shfl_xor(sum, o);
      sq  += __shfl_xor(sq,  o);
    }
    const float mu = sum * (1.0f / (float)EMB);
    const float r  = rsqrtf(sq * (1.0f / (float)EMB) - mu * mu + 1e-5f);
    #pragma unroll
    for (int j = 0; j < 12; ++j) {
      const int col = j * 16 + fr;
      X[(size_t)row * EMB + col] = v[j];
      Hout[(size_t)row * EMB + col] = __float2bfloat16((v[j] - mu) * r * g[col] + b[col]);
    }
  }
}

// ---------------------------------------------------------------- flash attention, KT=128, prefetched
// q pre-scaled by ATT_SCALE; heavy-first block ordering
__global__ __launch_bounds__(256) void flash_attn(
    const __hip_bfloat16* __restrict__ qh, const __hip_bfloat16* __restrict__ kh,
    const __hip_bfloat16* __restrict__ vh, __hip_bfloat16* __restrict__ att) {
  constexpr int QT = 128, KT = 128;
  constexpr int LK = 40;    // Ks row stride (80B, odd x16B -> conflict-free)
  constexpr int LS = 136;   // Vs/Ps row stride (272B, odd x16B)
  __shared__ __hip_bfloat16 Ks[KT * LK];      // [s][d]  10.2 KB
  __shared__ __hip_bfloat16 Vs[HSZ * LS];     // [d][s]   8.7 KB
  __shared__ __hip_bfloat16 Ps[4][32 * LS];   // per-wave P [q][s] 34.8 KB
  const int qt = (SEQ / QT - 1) - blockIdx.x;  // heavy blocks dispatch first
  const int h = blockIdx.y, b = blockIdx.z;
  const int tid = threadIdx.x, wid = tid >> 6, lane = tid & 63;
  const int q0 = qt * QT;
  const size_t hb = ((size_t)(b * NH + h)) * SEQ * HSZ;
  const int fr = lane & 15, fg = lane >> 4;

  bh8 aq[2];
  #pragma unroll
  for (int rt = 0; rt < 2; ++rt)
    aq[rt] = *reinterpret_cast<const bh8*>(
        qh + hb + (size_t)(q0 + wid * 32 + rt * 16 + fr) * HSZ + fg * 8);

  f32x4 o[2][2];
  float lp[2][4];
  #pragma unroll
  for (int rt = 0; rt < 2; ++rt) {
    #pragma unroll
    for (int ct = 0; ct < 2; ++ct) o[rt][ct] = (f32x4){0.f, 0.f, 0.f, 0.f};
    #pragma unroll
    for (int rr = 0; rr < 4; ++rr) lp[rt][rr] = 0.f;
  }

  const int nt = qt + 1;
  const int sr = tid >> 1;               // 0..127
  const int dbase = (tid & 1) * 16;      // 0 / 16
  bh8 kv[2], vv[2];
  #pragma unroll
  for (int i = 0; i < 2; ++i) {
    kv[i] = *reinterpret_cast<const bh8*>(kh + hb + (size_t)sr * HSZ + dbase + i * 8);
    vv[i] = *reinterpret_cast<const bh8*>(vh + hb + (size_t)sr * HSZ + dbase + i * 8);
  }

  for (int it = 0; it < nt; ++it) {
    const int s0 = it * KT;
    __syncthreads();
    #pragma unroll
    for (int i = 0; i < 2; ++i) {
      const int d0 = dbase + i * 8;
      *reinterpret_cast<bh8*>(&Ks[sr * LK + d0]) = kv[i];
      short tmp[8]; *reinterpret_cast<bh8*>(tmp) = vv[i];
      #pragma unroll
      for (int j = 0; j < 8; ++j)
        Vs[(d0 + j) * LS + sr] = *reinterpret_cast<__hip_bfloat16*>(&tmp[j]);
    }
    __syncthreads();
    if (it + 1 < nt) {
      const size_t nb_ = hb + (size_t)(s0 + KT + sr) * HSZ + dbase;
      #pragma unroll
      for (int i = 0; i < 2; ++i) {
        kv[i] = *reinterpret_cast<const bh8*>(kh + nb_ + i * 8);
        vv[i] = *reinterpret_cast<const bh8*>(vh + nb_ + i * 8);
      }
    }

    // S = Q K^T  (8 s-tiles of 16)
    f32x4 sfr[2][8];
    #pragma unroll
    for (int rt = 0; rt < 2; ++rt)
      #pragma unroll
      for (int st = 0; st < 8; ++st) {
        const bh8 bf_ = *reinterpret_cast<const bh8*>(&Ks[(st * 16 + fr) * LK + fg * 8]);
        sfr[rt][st] = __builtin_amdgcn_mfma_f32_16x16x32_bf16(
            aq[rt], bf_, (f32x4){0.f, 0.f, 0.f, 0.f}, 0, 0, 0);
      }

    // exp (no max subtraction: scores O(1)); per-thread partial row sums
    __hip_bfloat16* Pw = Ps[wid];
    const bool diag = (s0 + KT - 1 > q0 + wid * 32);
    #pragma unroll
    for (int rt = 0; rt < 2; ++rt) {
      #pragma unroll
      for (int rr = 0; rr < 4; ++rr) {
        float pr[8];
        if (diag) {
          const int qa = q0 + wid * 32 + rt * 16 + fg * 4 + rr;
          #pragma unroll
          for (int st = 0; st < 8; ++st) {
            const int sa = s0 + st * 16 + fr;
            pr[st] = (sa > qa) ? 0.f : __expf(sfr[rt][st][rr]);
          }
        } else {
          #pragma unroll
          for (int st = 0; st < 8; ++st) pr[st] = __expf(sfr[rt][st][rr]);
        }
        float ls = 0.f;
        #pragma unroll
        for (int st = 0; st < 8; ++st) ls += pr[st];
        lp[rt][rr] += ls;
        #pragma unroll
        for (int st = 0; st < 8; ++st)
          Pw[(rt * 16 + fg * 4 + rr) * LS + st * 16 + fr] = __float2bfloat16(pr[st]);
      }
    }

    // O += P V  (K=128 -> 4 k-steps)
    #pragma unroll
    for (int ks = 0; ks < 4; ++ks) {
      bh8 vb_[2];
      #pragma unroll
      for (int ct = 0; ct < 2; ++ct)
        vb_[ct] = *reinterpret_cast<const bh8*>(&Vs[(ct * 16 + fr) * LS + ks * 32 + fg * 8]);
      #pragma unroll
      for (int rt = 0; rt < 2; ++rt) {
        const bh8 pa = *reinterpret_cast<const bh8*>(&Pw[(rt * 16 + fr) * LS + ks * 32 + fg * 8]);
        #pragma unroll
        for (int ct = 0; ct < 2; ++ct)
          o[rt][ct] = __builtin_amdgcn_mfma_f32_16x16x32_bf16(pa, vb_[ct], o[rt][ct], 0, 0, 0);
      }
    }
  }

  // final row-sum reduce + epilogue
  #pragma unroll
  for (int rt = 0; rt < 2; ++rt)
    #pragma unroll
    for (int rr = 0; rr < 4; ++rr) {
      float s = lp[rt][rr];
      #pragma unroll
      for (int off = 8; off; off >>= 1) s += __shfl_xor(s, off);
      const float inv = 1.0f / s;
      const int qa = q0 + wid * 32 + rt * 16 + fg * 4 + rr;
      #pragma unroll
      for (int ct = 0; ct < 2; ++ct) {
        const int d = ct * 16 + fr;
        att[((size_t)(b * SEQ + qa)) * EMB + h * HSZ + d] =
            __float2bfloat16(o[rt][ct][rr] * inv);
      }
    }
}

// ---------------------------------------------------------------- launcher
extern "C" void kernel_launch(void* const* d_in, const int* in_sizes, int n_in,
                              void* d_out, int out_size, void* d_ws, size_t ws_size,
                              hipStream_t stream) {
  const int*   idx   = (const int*)  d_in[0];
  const float* tok   = (const float*)d_in[1];
  const float* Wq    = (const float*)d_in[2];
  const float* Wk    = (const float*)d_in[3];
  const float* Wv    = (const float*)d_in[4];
  const float* Wo    = (const float*)d_in[5];
  const float* W1    = (const float*)d_in[6];
  const float* W2    = (const float*)d_in[7];
  const float* ln1g  = (const float*)d_in[8];
  const float* ln1b  = (const float*)d_in[9];
  const float* ln2g  = (const float*)d_in[10];
  const float* ln2b  = (const float*)d_in[11];
  const float* lnfg  = (const float*)d_in[12];
  const float* lnfb  = (const float*)d_in[13];
  const float* Wlm   = (const float*)d_in[14];
  float* out = (float*)d_out;

  const size_t NTE = (size_t)BT * EMB;
  char* ws = (char*)d_ws;
  float* x   = (float*)ws;                         ws += NTE * 4;
  __hip_bfloat16* qh   = (__hip_bfloat16*)ws;      ws += NTE * 2 * 3;  // q,k,v contiguous
  __hip_bfloat16* h    = (__hip_bfloat16*)ws;      ws += NTE * 2;
  __hip_bfloat16* att  = (__hip_bfloat16*)ws;      ws += NTE * 2;
  __hip_bfloat16* hid  = (__hip_bfloat16*)ws;      ws += NTE * 4 * 2;
  __hip_bfloat16* wqkv = (__hip_bfloat16*)ws;      ws += (size_t)NL * 576 * EMB * 2;
  __hip_bfloat16* wot  = (__hip_bfloat16*)ws;      ws += (size_t)NL * EMB * EMB * 2;
  __hip_bfloat16* w1t  = (__hip_bfloat16*)ws;      ws += (size_t)NL * EMB * EMB * 4 * 2;
  __hip_bfloat16* w2t  = (__hip_bfloat16*)ws;      ws += (size_t)NL * EMB * EMB * 4 * 2;
  __hip_bfloat16* wlt  = (__hip_bfloat16*)ws;

  wprep<<<3816, 256, 0, stream>>>(Wq, Wk, Wv, Wo, W1, W2, Wlm,
                                  wqkv, wot, w1t, w2t, wlt);
  embed_ln<<<BT / 4, 256, 0, stream>>>(idx, tok, ln1g, ln1b, x, h);

  const dim3 gQKV(576 / 64, BT / 128);            // (9,128)
  const dim3 gM  (EMB * 4 / 64, BT / 128);        // (12,128)
  const dim3 gV  ((VOCAB + 127) / 128, BT / 128); // (51,128)
  const dim3 gA  (SEQ / 128, NH, BATCH);          // (4,6,32)

  for (int l = 0; l < NL; ++l) {
    const size_t wo = (size_t)l * EMB * EMB;
    const size_t wm = (size_t)l * EMB * EMB * 4;
    gemm_big<3, 64><<<gQKV, 256, 0, stream>>>(h, wqkv + (size_t)l * 576 * EMB, qh, BT, 576, EMB);
    flash_attn<<<gA, 256, 0, stream>>>(qh, qh + NTE, qh + 2 * NTE, att);
    gemm_resln<<<BT / 32, 128, 0, stream>>>(att, wot + wo, x, h,
                                            ln2g + l * EMB, ln2b + l * EMB, EMB);
    gemm_big<2, 64><<<gM, 256, 0, stream>>>(h, w1t + wm, hid, BT, EMB * 4, EMB);
    const float* ng = (l == NL - 1) ? lnfg : ln1g + (l + 1) * EMB;
    const float* nb = (l == NL - 1) ? lnfb : ln1b + (l + 1) * EMB;
    gemm_resln<<<BT / 32, 128, 0, stream>>>(hid, w2t + wm, x, h, ng, nb, EMB * 4);
  }

  gemm_big<0, 128><<<gV, 256, 0, stream>>>(h, wlt, out, BT, VOCAB, EMB);
}